// Round 13
// baseline (116.409 us; speedup 1.0000x reference)
//
#include <hip/hip_runtime.h>

#define MAX_PATH_DISTANCE 5
#define NROW 8192
#define ROWS_PER_BKT 128
#define NBKT 64             // coarse buckets = src >> 7
#define SLICES 17
#define EPB 4096            // entries per stage/task
#define CAPB (SLICES * EPB) // 69632/bucket (exp 62.5K, +28 sigma)
#define CAPR 768            // per-row capacity (exp 488, +12.7 sigma)
#define BLK 512             // 8 waves/block
#define NWAVE 8             // per-wave hists in coarse
#define NHG 4               // shared hist groups in fine (wave pairs)
#define EPT 8               // entries per thread = EPB/BLK
#define RPB 4               // rows per block in se_rows

typedef float f32x4 __attribute__((ext_vector_type(4)));
typedef int   i32x4 __attribute__((ext_vector_type(4)));
typedef unsigned long long u64;
typedef u64 u64x2 __attribute__((ext_vector_type(2)));

// entry = [src:13 @38 | dst:13 @25 | key:25 @0], key = ((e+1)<<3)|bidx
// key order == edge order; key != 0.

__device__ __forceinline__ int clamp_bidx(int pl) {
    int c = pl < 1 ? 1 : (pl > MAX_PATH_DISTANCE ? MAX_PATH_DISTANCE : pl);
    return c - 1;
}

// ---- Pass 1: coarse counting-sort of edges into 64 buckets (R8, proven).
// Streaming inputs via nontemporal loads; also zeroes rcur for se_fine
// (stream order guarantees completion before fine starts).
__global__ __launch_bounds__(BLK) void se_coarse(
        const i32x4* __restrict__ src4, const i32x4* __restrict__ dst4,
        const i32x4* __restrict__ plen4,
        unsigned long long* __restrict__ bkt,
        unsigned int* __restrict__ bkt_cur,
        unsigned int* __restrict__ rcur, int E4) {
    __shared__ __align__(16) unsigned long long stage[EPB];          // 32 KB
    __shared__ unsigned int hist[NWAVE][NBKT], wb[NWAVE][NBKT];      // 4 KB
    __shared__ unsigned int base_l[NBKT], gbase[NBKT], s_total;
    const int tid = threadIdx.x;
    const int w   = tid >> 6;
    const int q0  = blockIdx.x * (EPB / 4);      // int4 index base

    // zero rcur for pass 2 (spread across blocks, one store each)
    for (int i = blockIdx.x * BLK + tid; i < NROW; i += gridDim.x * BLK)
        rcur[i] = 0u;

    for (int i = tid; i < NWAVE * NBKT; i += BLK) (&hist[0][0])[i] = 0u;
    __syncthreads();

    unsigned long long ent[EPT];
#pragma unroll
    for (int g = 0; g < 2; ++g) {
        int q = q0 + g * BLK + tid;
        if (q < E4) {
            i32x4 s = __builtin_nontemporal_load(&src4[q]);
            i32x4 d = __builtin_nontemporal_load(&dst4[q]);
            i32x4 p = __builtin_nontemporal_load(&plen4[q]);
            int ss[4] = {s.x, s.y, s.z, s.w};
            int dd[4] = {d.x, d.y, d.z, d.w};
            int pp[4] = {p.x, p.y, p.z, p.w};
#pragma unroll
            for (int c = 0; c < 4; ++c) {
                int e = (q << 2) + c;
                unsigned int key = ((unsigned int)(e + 1) << 3)
                                 | (unsigned int)clamp_bidx(pp[c]);
                unsigned long long v =
                      ((unsigned long long)(unsigned int)ss[c] << 38)
                    | ((unsigned long long)(unsigned int)dd[c] << 25)
                    | (unsigned long long)key;
                ent[g * 4 + c] = v;
                atomicAdd(&hist[w][(unsigned int)(v >> 45)], 1u);
            }
        } else {
#pragma unroll
            for (int c = 0; c < 4; ++c) ent[g * 4 + c] = 0ull;
        }
    }
    __syncthreads();

    if (tid < NBKT) {
        unsigned int t = 0;
#pragma unroll
        for (int ww = 0; ww < NWAVE; ++ww) t += hist[ww][tid];
        base_l[tid] = t;
    }
    __syncthreads();
    if (tid == 0) {
        unsigned int run = 0;
        for (int i = 0; i < NBKT; ++i) {
            unsigned int t = base_l[i]; base_l[i] = run; run += t;
        }
        s_total = run;
    }
    __syncthreads();
    if (tid < NBKT) {
        unsigned int t = base_l[tid], tot = 0;
#pragma unroll
        for (int ww = 0; ww < NWAVE; ++ww) {
            wb[ww][tid] = t; t += hist[ww][tid]; tot += hist[ww][tid];
        }
        gbase[tid] = atomicAdd(&bkt_cur[tid], tot);
    }
    __syncthreads();

#pragma unroll
    for (int j = 0; j < EPT; ++j) {
        if (ent[j]) {
            unsigned int bb = (unsigned int)(ent[j] >> 45);
            unsigned int p  = atomicAdd(&wb[w][bb], 1u);
            stage[p] = ent[j];
        }
    }
    __syncthreads();

    const unsigned int total = s_total;
    for (unsigned int i = tid; i < total; i += BLK) {   // same-bucket runs
        unsigned long long v = stage[i];                // -> coalesced
        unsigned int bb  = (unsigned int)(v >> 45);
        unsigned int pos = gbase[bb] + (i - base_l[bb]);
        if (pos < CAPB) bkt[(size_t)bb * CAPB + pos] = v;
    }
}

// ---- Pass 2: fine counting-sort of bucket slices into per-row bins.
// 16B (2-entry) nontemporal loads of the bucket stream.
__global__ __launch_bounds__(BLK) void se_fine(
        const unsigned long long* __restrict__ bkt,
        const unsigned int* __restrict__ bkt_cur,
        unsigned long long* __restrict__ rbins,
        unsigned int* __restrict__ rcur) {
    __shared__ __align__(16) unsigned long long stage[EPB];            // 32 KB
    __shared__ unsigned int hist[NHG][ROWS_PER_BKT];                    // 2 KB
    __shared__ unsigned int wb[NHG][ROWS_PER_BKT];                      // 2 KB
    __shared__ unsigned int base_l[ROWS_PER_BKT], gbase[ROWS_PER_BKT], s_total;
    const int tid = threadIdx.x;
    const int w   = tid >> 7;           // wave pair
    const int b   = blockIdx.x / SLICES;
    const int sl  = blockIdx.x % SLICES;

    unsigned int cnt = bkt_cur[b]; if (cnt > CAPB) cnt = CAPB;
    const int i0 = sl * EPB;
    int n = (int)cnt - i0;
    if (n <= 0) return;                 // block-uniform -> safe early exit
    if (n > EPB) n = EPB;

    for (int i = tid; i < NHG * ROWS_PER_BKT; i += BLK) (&hist[0][0])[i] = 0u;
    __syncthreads();

    const u64x2* bp2 =
        reinterpret_cast<const u64x2*>(bkt + (size_t)b * CAPB + i0);
    unsigned long long ent[EPT];
#pragma unroll
    for (int j2 = 0; j2 < EPT / 2; ++j2) {           // pair index
        int i2 = j2 * BLK + tid;                     // pairs 0..2047
        u64x2 pr = __builtin_nontemporal_load(&bp2[i2]);  // always in-bounds
        int i = i2 * 2;                              // of the full slice
        ent[j2 * 2]     = (i < n)     ? pr.x : 0ull;
        ent[j2 * 2 + 1] = (i + 1 < n) ? pr.y : 0ull;
        if (ent[j2 * 2])
            atomicAdd(&hist[w][(unsigned int)(ent[j2 * 2] >> 38) & 127u], 1u);
        if (ent[j2 * 2 + 1])
            atomicAdd(&hist[w][(unsigned int)(ent[j2 * 2 + 1] >> 38) & 127u], 1u);
    }
    __syncthreads();

    if (tid < ROWS_PER_BKT) {
        unsigned int t = 0;
#pragma unroll
        for (int ww = 0; ww < NHG; ++ww) t += hist[ww][tid];
        base_l[tid] = t;
    }
    __syncthreads();
    if (tid == 0) {
        unsigned int run = 0;
        for (int i = 0; i < ROWS_PER_BKT; ++i) {
            unsigned int t = base_l[i]; base_l[i] = run; run += t;
        }
        s_total = run;
    }
    __syncthreads();
    if (tid < ROWS_PER_BKT) {
        unsigned int t = base_l[tid], tot = 0;
#pragma unroll
        for (int ww = 0; ww < NHG; ++ww) {
            wb[ww][tid] = t; t += hist[ww][tid]; tot += hist[ww][tid];
        }
        gbase[tid] = atomicAdd(&rcur[b * ROWS_PER_BKT + tid], tot);
    }
    __syncthreads();

#pragma unroll
    for (int j = 0; j < EPT; ++j) {
        if (ent[j]) {
            unsigned int rl = (unsigned int)(ent[j] >> 38) & 127u;
            unsigned int p  = atomicAdd(&wb[w][rl], 1u);
            stage[p] = ent[j];
        }
    }
    __syncthreads();

    const unsigned int total = s_total;
    for (unsigned int i = tid; i < total; i += BLK) {
        unsigned long long v = stage[i];
        unsigned int s   = (unsigned int)((v >> 38) & 0x1FFFu);
        unsigned int rl  = s & 127u;
        unsigned int pos = gbase[rl] + (i - base_l[rl]);
        if (pos < CAPR) rbins[(size_t)s * CAPR + pos] = v;
    }
}

// ---- Pass 3: four rows per block; one-pass resolve (atomicMax leaves the
// winning key in LDS; key -> b[key&7] via 5-entry LDS LUT during the write
// sweep). 16B nontemporal rbins loads; nontemporal output stores.
__global__ __launch_bounds__(BLK) void se_rows(
        const unsigned long long* __restrict__ rbins,
        const uint4* __restrict__ rcur4,
        const float* __restrict__ bias,
        float* __restrict__ out) {
    __shared__ unsigned int lds[NROW];                                // 32 KB
    __shared__ float lbias[8];
    const int tid = threadIdx.x;
    const int r0  = blockIdx.x * RPB;

    if (tid < 8) lbias[tid] = (tid < MAX_PATH_DISTANCE) ? bias[tid] : 0.0f;

    uint4 cv = rcur4[blockIdx.x];
    unsigned int cnt[RPB] = {cv.x, cv.y, cv.z, cv.w};
#pragma unroll
    for (int k = 0; k < RPB; ++k) if (cnt[k] > CAPR) cnt[k] = CAPR;

    // prefetch all rows' entries up front: thread t holds entries 2t,2t+1
    // (2*BLK = 1024 >= CAPR) via one 16B load per row.
    unsigned long long e0[RPB], e1[RPB];
#pragma unroll
    for (int k = 0; k < RPB; ++k) {
        e0[k] = 0ull; e1[k] = 0ull;
        if ((unsigned int)(2 * tid) < cnt[k]) {
            const u64x2* bp2 = reinterpret_cast<const u64x2*>(
                rbins + (size_t)(r0 + k) * CAPR);
            u64x2 pr = __builtin_nontemporal_load(&bp2[tid]);
            e0[k] = pr.x;
            e1[k] = ((unsigned int)(2 * tid + 1) < cnt[k]) ? pr.y : 0ull;
        }
    }

#pragma unroll
    for (int k = 0; k < RPB; ++k) {
        if (k) __syncthreads();           // previous row's LDS reads done
        for (int i = tid; i < NROW; i += BLK) lds[i] = 0u;
        __syncthreads();

        if (e0[k]) atomicMax(&lds[(unsigned int)((e0[k] >> 25) & 0x1FFFu)],
                             (unsigned int)(e0[k] & 0x1FFFFFFu));
        if (e1[k]) atomicMax(&lds[(unsigned int)((e1[k] >> 25) & 0x1FFFu)],
                             (unsigned int)(e1[k] & 0x1FFFFFFu));
        __syncthreads();

        float* orow = out + (size_t)(r0 + k) * NROW;
        const uint4* l4 = reinterpret_cast<const uint4*>(lds);
#pragma unroll
        for (int q = 0; q < NROW / 4 / BLK; ++q) {
            uint4 u = l4[q * BLK + tid];
            f32x4 f;
            f.x = u.x ? lbias[u.x & 7u] : 0.0f;
            f.y = u.y ? lbias[u.y & 7u] : 0.0f;
            f.z = u.z ? lbias[u.z & 7u] : 0.0f;
            f.w = u.w ? lbias[u.w & 7u] : 0.0f;
            __builtin_nontemporal_store(
                f, reinterpret_cast<f32x4*>(orow) + q * BLK + tid);
        }
    }
}

// ---------------- fallback path (proven in R1): global atomicMax ----------------

__global__ void se_scatter_keys(const int* __restrict__ src,
                                const int* __restrict__ dst,
                                const int* __restrict__ plen,
                                unsigned int* __restrict__ out,
                                int E, int N) {
    int e = blockIdx.x * blockDim.x + threadIdx.x;
    if (e >= E) return;
    unsigned int key = ((unsigned int)(e + 1) << 3)
                     | (unsigned int)clamp_bidx(plen[e]);
    atomicMax(&out[(size_t)src[e] * (size_t)N + (size_t)dst[e]], key);
}

__global__ void se_resolve(const int* __restrict__ src,
                           const int* __restrict__ dst,
                           const int* __restrict__ plen,
                           const float* __restrict__ b,
                           unsigned int* __restrict__ out,
                           int E, int N) {
    int e = blockIdx.x * blockDim.x + threadIdx.x;
    if (e >= E) return;
    unsigned int key = ((unsigned int)(e + 1) << 3)
                     | (unsigned int)clamp_bidx(plen[e]);
    size_t off = (size_t)src[e] * (size_t)N + (size_t)dst[e];
    if (out[off] == key) {
        reinterpret_cast<float*>(out)[off] = b[key & 7u];
    }
}

// --------------------------------------------------------------------------------

extern "C" void kernel_launch(void* const* d_in, const int* in_sizes, int n_in,
                              void* d_out, int out_size, void* d_ws, size_t ws_size,
                              hipStream_t stream) {
    // inputs: x [N,128] f32, b [5] f32, src [E] i32, dst [E] i32, path_len [E] i32
    const float* b    = (const float*)d_in[1];
    const int*   src  = (const int*)d_in[2];
    const int*   dst  = (const int*)d_in[3];
    const int*   plen = (const int*)d_in[4];

    const int N = in_sizes[0] / 128;   // 8192
    const int E = in_sizes[2];         // 4,000,000

    // ws layout: [rbins][bkt][rcur(NROW)][bcur(NBKT)]  (rcur 16B-aligned for
    // the uint4 cursor loads in se_rows; rbins rows 16B-aligned: CAPR*8=6144B)
    const size_t rbins_bytes = (size_t)NROW * CAPR * sizeof(unsigned long long);
    const size_t bkt_bytes   = (size_t)NBKT * CAPB * sizeof(unsigned long long);
    const size_t cur_bytes   = (size_t)(NROW + NBKT) * sizeof(unsigned int);
    const size_t need = rbins_bytes + bkt_bytes + cur_bytes;

    if (N == NROW && (unsigned int)E < (1u << 22) && (E % 4) == 0 &&
        ws_size >= need) {
        unsigned long long* rbins = (unsigned long long*)d_ws;
        unsigned long long* bktp  = (unsigned long long*)((char*)d_ws + rbins_bytes);
        unsigned int* rcur = (unsigned int*)((char*)d_ws + rbins_bytes + bkt_bytes);
        unsigned int* bcur = rcur + NROW;

        (void)hipMemsetAsync(bcur, 0, NBKT * sizeof(unsigned int), stream);
        se_coarse<<<(E + EPB - 1) / EPB, BLK, 0, stream>>>(
            (const i32x4*)src, (const i32x4*)dst, (const i32x4*)plen,
            bktp, bcur, rcur, E / 4);
        se_fine<<<NBKT * SLICES, BLK, 0, stream>>>(bktp, bcur, rbins, rcur);
        se_rows<<<NROW / RPB, BLK, 0, stream>>>(rbins, (const uint4*)rcur, b,
                                                (float*)d_out);
    } else {
        // fallback: R1 path (generic, proven)
        const int block = 256;
        const int gridE = (E + block - 1) / block;
        (void)hipMemsetAsync(d_out, 0, (size_t)out_size * sizeof(float), stream);
        se_scatter_keys<<<gridE, block, 0, stream>>>(src, dst, plen,
                                                     (unsigned int*)d_out, E, N);
        se_resolve<<<gridE, block, 0, stream>>>(src, dst, plen, b,
                                                (unsigned int*)d_out, E, N);
    }
}

// Round 14
// 105.367 us; speedup vs baseline: 1.1048x; 1.1048x over previous
//
#include <hip/hip_runtime.h>

#define MAX_PATH_DISTANCE 5
#define NROW 8192
#define ROWS_PER_BKT 128
#define NBKT 64             // coarse buckets = src >> 7
#define SLICES 17
#define EPB 4096            // entries per stage/task
#define CAPB (SLICES * EPB) // 69632/bucket (exp 62.5K, +28 sigma)
#define CAPR 768            // per-row capacity (exp 488, +12.7 sigma)
#define BLK 512             // 8 waves/block
#define NWAVE 8             // per-wave hists in coarse
#define NHG 4               // shared hist groups in fine (wave pairs)
#define EPT 8               // entries per thread = EPB/BLK
#define RPB 4               // rows per block in se_rows

typedef float f32x4 __attribute__((ext_vector_type(4)));

// entry = [src:13 @38 | dst:13 @25 | key:25 @0], key = ((e+1)<<3)|bidx
// key order == edge order; key != 0.

__device__ __forceinline__ int clamp_bidx(int pl) {
    int c = pl < 1 ? 1 : (pl > MAX_PATH_DISTANCE ? MAX_PATH_DISTANCE : pl);
    return c - 1;
}

// ---- Pass 1: coarse counting-sort of edges into 64 buckets (R8, proven) ----
__global__ __launch_bounds__(BLK) void se_coarse(
        const int4* __restrict__ src4, const int4* __restrict__ dst4,
        const int4* __restrict__ plen4,
        unsigned long long* __restrict__ bkt,
        unsigned int* __restrict__ bkt_cur, int E4) {
    __shared__ __align__(16) unsigned long long stage[EPB];          // 32 KB
    __shared__ unsigned int hist[NWAVE][NBKT], wb[NWAVE][NBKT];      // 4 KB
    __shared__ unsigned int base_l[NBKT], gbase[NBKT], s_total;
    const int tid = threadIdx.x;
    const int w   = tid >> 6;
    const int q0  = blockIdx.x * (EPB / 4);      // int4 index base

    for (int i = tid; i < NWAVE * NBKT; i += BLK) (&hist[0][0])[i] = 0u;
    __syncthreads();

    unsigned long long ent[EPT];
#pragma unroll
    for (int g = 0; g < 2; ++g) {
        int q = q0 + g * BLK + tid;
        if (q < E4) {
            int4 s = src4[q], d = dst4[q], p = plen4[q];
            int ss[4] = {s.x, s.y, s.z, s.w};
            int dd[4] = {d.x, d.y, d.z, d.w};
            int pp[4] = {p.x, p.y, p.z, p.w};
#pragma unroll
            for (int c = 0; c < 4; ++c) {
                int e = (q << 2) + c;
                unsigned int key = ((unsigned int)(e + 1) << 3)
                                 | (unsigned int)clamp_bidx(pp[c]);
                unsigned long long v =
                      ((unsigned long long)(unsigned int)ss[c] << 38)
                    | ((unsigned long long)(unsigned int)dd[c] << 25)
                    | (unsigned long long)key;
                ent[g * 4 + c] = v;
                atomicAdd(&hist[w][(unsigned int)(v >> 45)], 1u);
            }
        } else {
#pragma unroll
            for (int c = 0; c < 4; ++c) ent[g * 4 + c] = 0ull;
        }
    }
    __syncthreads();

    if (tid < NBKT) {
        unsigned int t = 0;
#pragma unroll
        for (int ww = 0; ww < NWAVE; ++ww) t += hist[ww][tid];
        base_l[tid] = t;
    }
    __syncthreads();
    if (tid == 0) {
        unsigned int run = 0;
        for (int i = 0; i < NBKT; ++i) {
            unsigned int t = base_l[i]; base_l[i] = run; run += t;
        }
        s_total = run;
    }
    __syncthreads();
    if (tid < NBKT) {
        unsigned int t = base_l[tid], tot = 0;
#pragma unroll
        for (int ww = 0; ww < NWAVE; ++ww) {
            wb[ww][tid] = t; t += hist[ww][tid]; tot += hist[ww][tid];
        }
        gbase[tid] = atomicAdd(&bkt_cur[tid], tot);
    }
    __syncthreads();

#pragma unroll
    for (int j = 0; j < EPT; ++j) {
        if (ent[j]) {
            unsigned int bb = (unsigned int)(ent[j] >> 45);
            unsigned int p  = atomicAdd(&wb[w][bb], 1u);
            stage[p] = ent[j];
        }
    }
    __syncthreads();

    const unsigned int total = s_total;
    for (unsigned int i = tid; i < total; i += BLK) {   // same-bucket runs
        unsigned long long v = stage[i];                // -> coalesced
        unsigned int bb  = (unsigned int)(v >> 45);
        unsigned int pos = gbase[bb] + (i - base_l[bb]);
        if (pos < CAPB) bkt[(size_t)bb * CAPB + pos] = v;
    }
}

// ---- Pass 2: fine counting-sort of bucket slices into per-row bins (R8) ----
__global__ __launch_bounds__(BLK) void se_fine(
        const unsigned long long* __restrict__ bkt,
        const unsigned int* __restrict__ bkt_cur,
        unsigned long long* __restrict__ rbins,
        unsigned int* __restrict__ rcur) {
    __shared__ __align__(16) unsigned long long stage[EPB];            // 32 KB
    __shared__ unsigned int hist[NHG][ROWS_PER_BKT];                    // 2 KB
    __shared__ unsigned int wb[NHG][ROWS_PER_BKT];                      // 2 KB
    __shared__ unsigned int base_l[ROWS_PER_BKT], gbase[ROWS_PER_BKT], s_total;
    const int tid = threadIdx.x;
    const int w   = tid >> 7;           // wave pair
    const int b   = blockIdx.x / SLICES;
    const int sl  = blockIdx.x % SLICES;

    unsigned int cnt = bkt_cur[b]; if (cnt > CAPB) cnt = CAPB;
    const int i0 = sl * EPB;
    int n = (int)cnt - i0;
    if (n <= 0) return;                 // block-uniform -> safe early exit
    if (n > EPB) n = EPB;

    for (int i = tid; i < NHG * ROWS_PER_BKT; i += BLK) (&hist[0][0])[i] = 0u;
    __syncthreads();

    const unsigned long long* bp = bkt + (size_t)b * CAPB + i0;
    unsigned long long ent[EPT];
#pragma unroll
    for (int j = 0; j < EPT; ++j) {
        int i = j * BLK + tid;
        ent[j] = 0ull;
        if (i < n) {
            ent[j] = bp[i];
            atomicAdd(&hist[w][(unsigned int)(ent[j] >> 38) & 127u], 1u);
        }
    }
    __syncthreads();

    if (tid < ROWS_PER_BKT) {
        unsigned int t = 0;
#pragma unroll
        for (int ww = 0; ww < NHG; ++ww) t += hist[ww][tid];
        base_l[tid] = t;
    }
    __syncthreads();
    if (tid == 0) {
        unsigned int run = 0;
        for (int i = 0; i < ROWS_PER_BKT; ++i) {
            unsigned int t = base_l[i]; base_l[i] = run; run += t;
        }
        s_total = run;
    }
    __syncthreads();
    if (tid < ROWS_PER_BKT) {
        unsigned int t = base_l[tid], tot = 0;
#pragma unroll
        for (int ww = 0; ww < NHG; ++ww) {
            wb[ww][tid] = t; t += hist[ww][tid]; tot += hist[ww][tid];
        }
        gbase[tid] = atomicAdd(&rcur[b * ROWS_PER_BKT + tid], tot);
    }
    __syncthreads();

#pragma unroll
    for (int j = 0; j < EPT; ++j) {
        if (ent[j]) {
            unsigned int rl = (unsigned int)(ent[j] >> 38) & 127u;
            unsigned int p  = atomicAdd(&wb[w][rl], 1u);
            stage[p] = ent[j];
        }
    }
    __syncthreads();

    const unsigned int total = s_total;
    for (unsigned int i = tid; i < total; i += BLK) {
        unsigned long long v = stage[i];
        unsigned int s   = (unsigned int)((v >> 38) & 0x1FFFu);
        unsigned int rl  = s & 127u;
        unsigned int pos = gbase[rl] + (i - base_l[rl]);
        if (pos < CAPR) rbins[(size_t)s * CAPR + pos] = v;
    }
}

// ---- Pass 3: four rows per block; ONE-PASS resolve (atomicMax leaves the
// winning key in LDS; key -> b[key&7] mapped during the write sweep via a
// 5-entry LDS LUT in banks 0..4). Nontemporal output stores (never re-read).
__global__ __launch_bounds__(BLK) void se_rows(
        const unsigned long long* __restrict__ rbins,
        const uint4* __restrict__ rcur4,
        const float* __restrict__ bias,
        float* __restrict__ out) {
    __shared__ unsigned int lds[NROW];                                // 32 KB
    __shared__ float lbias[8];
    const int tid = threadIdx.x;
    const int r0  = blockIdx.x * RPB;

    if (tid < 8) lbias[tid] = (tid < MAX_PATH_DISTANCE) ? bias[tid] : 0.0f;

    uint4 cv = rcur4[blockIdx.x];
    unsigned int cnt[RPB] = {cv.x, cv.y, cv.z, cv.w};
#pragma unroll
    for (int k = 0; k < RPB; ++k) if (cnt[k] > CAPR) cnt[k] = CAPR;

    // prefetch all rows' entries up front (8 independent loads in flight)
    unsigned long long e0[RPB], e1[RPB];
#pragma unroll
    for (int k = 0; k < RPB; ++k) {
        const unsigned long long* bp = rbins + (size_t)(r0 + k) * CAPR;
        e0[k] = ((unsigned int)tid < cnt[k])       ? bp[tid]       : 0ull;
        e1[k] = ((unsigned int)tid + BLK < cnt[k]) ? bp[tid + BLK] : 0ull;
    }

#pragma unroll
    for (int k = 0; k < RPB; ++k) {
        if (k) __syncthreads();           // previous row's LDS reads done
        for (int i = tid; i < NROW; i += BLK) lds[i] = 0u;
        __syncthreads();

        if (e0[k]) atomicMax(&lds[(unsigned int)((e0[k] >> 25) & 0x1FFFu)],
                             (unsigned int)(e0[k] & 0x1FFFFFFu));
        if (e1[k]) atomicMax(&lds[(unsigned int)((e1[k] >> 25) & 0x1FFFu)],
                             (unsigned int)(e1[k] & 0x1FFFFFFu));
        __syncthreads();

        float* orow = out + (size_t)(r0 + k) * NROW;
        const uint4* l4 = reinterpret_cast<const uint4*>(lds);
#pragma unroll
        for (int q = 0; q < NROW / 4 / BLK; ++q) {
            uint4 u = l4[q * BLK + tid];
            f32x4 f;
            f.x = u.x ? lbias[u.x & 7u] : 0.0f;
            f.y = u.y ? lbias[u.y & 7u] : 0.0f;
            f.z = u.z ? lbias[u.z & 7u] : 0.0f;
            f.w = u.w ? lbias[u.w & 7u] : 0.0f;
            __builtin_nontemporal_store(
                f, reinterpret_cast<f32x4*>(orow) + q * BLK + tid);
        }
    }
}

// ---------------- fallback path (proven in R1): global atomicMax ----------------

__global__ void se_scatter_keys(const int* __restrict__ src,
                                const int* __restrict__ dst,
                                const int* __restrict__ plen,
                                unsigned int* __restrict__ out,
                                int E, int N) {
    int e = blockIdx.x * blockDim.x + threadIdx.x;
    if (e >= E) return;
    unsigned int key = ((unsigned int)(e + 1) << 3)
                     | (unsigned int)clamp_bidx(plen[e]);
    atomicMax(&out[(size_t)src[e] * (size_t)N + (size_t)dst[e]], key);
}

__global__ void se_resolve(const int* __restrict__ src,
                           const int* __restrict__ dst,
                           const int* __restrict__ plen,
                           const float* __restrict__ b,
                           unsigned int* __restrict__ out,
                           int E, int N) {
    int e = blockIdx.x * blockDim.x + threadIdx.x;
    if (e >= E) return;
    unsigned int key = ((unsigned int)(e + 1) << 3)
                     | (unsigned int)clamp_bidx(plen[e]);
    size_t off = (size_t)src[e] * (size_t)N + (size_t)dst[e];
    if (out[off] == key) {
        reinterpret_cast<float*>(out)[off] = b[key & 7u];
    }
}

// --------------------------------------------------------------------------------

extern "C" void kernel_launch(void* const* d_in, const int* in_sizes, int n_in,
                              void* d_out, int out_size, void* d_ws, size_t ws_size,
                              hipStream_t stream) {
    // inputs: x [N,128] f32, b [5] f32, src [E] i32, dst [E] i32, path_len [E] i32
    const float* b    = (const float*)d_in[1];
    const int*   src  = (const int*)d_in[2];
    const int*   dst  = (const int*)d_in[3];
    const int*   plen = (const int*)d_in[4];

    const int N = in_sizes[0] / 128;   // 8192
    const int E = in_sizes[2];         // 4,000,000

    // ws layout: [rbins][bkt][rcur(NROW)][bcur(NBKT)]  (cursors contiguous;
    // rcur offset is 16B-aligned for the uint4 cursor loads in se_rows)
    const size_t rbins_bytes = (size_t)NROW * CAPR * sizeof(unsigned long long);
    const size_t bkt_bytes   = (size_t)NBKT * CAPB * sizeof(unsigned long long);
    const size_t cur_bytes   = (size_t)(NROW + NBKT) * sizeof(unsigned int);
    const size_t need = rbins_bytes + bkt_bytes + cur_bytes;

    if (N == NROW && (unsigned int)E < (1u << 22) && (E % 4) == 0 &&
        ws_size >= need) {
        unsigned long long* rbins = (unsigned long long*)d_ws;
        unsigned long long* bktp  = (unsigned long long*)((char*)d_ws + rbins_bytes);
        unsigned int* rcur = (unsigned int*)((char*)d_ws + rbins_bytes + bkt_bytes);
        unsigned int* bcur = rcur + NROW;

        (void)hipMemsetAsync(rcur, 0, cur_bytes, stream);
        se_coarse<<<(E + EPB - 1) / EPB, BLK, 0, stream>>>(
            (const int4*)src, (const int4*)dst, (const int4*)plen,
            bktp, bcur, E / 4);
        se_fine<<<NBKT * SLICES, BLK, 0, stream>>>(bktp, bcur, rbins, rcur);
        se_rows<<<NROW / RPB, BLK, 0, stream>>>(rbins, (const uint4*)rcur, b,
                                                (float*)d_out);
    } else {
        // fallback: R1 path (generic, proven)
        const int block = 256;
        const int gridE = (E + block - 1) / block;
        (void)hipMemsetAsync(d_out, 0, (size_t)out_size * sizeof(float), stream);
        se_scatter_keys<<<gridE, block, 0, stream>>>(src, dst, plen,
                                                     (unsigned int*)d_out, E, N);
        se_resolve<<<gridE, block, 0, stream>>>(src, dst, plen, b,
                                                (unsigned int*)d_out, E, N);
    }
}